// Round 8
// baseline (367.872 us; speedup 1.0000x reference)
//
#include <hip/hip_runtime.h>
#include <hip/hip_bf16.h>

typedef __attribute__((ext_vector_type(8))) short short8;
typedef __attribute__((ext_vector_type(4))) short short4_t;
typedef __attribute__((ext_vector_type(4))) float float4_t;
typedef unsigned short ushort;

#define HW 4096
#define CC 256
#define NBATCH 4
#define SEQ ((size_t)NBATCH * HW)

static __device__ __forceinline__ unsigned short f2b(float f) {
    union { float f; unsigned u; } v; v.f = f;
    unsigned r = v.u + 0x7FFF + ((v.u >> 16) & 1);   // RNE
    return (unsigned short)(r >> 16);
}

// ---- kernel 1: x[n][c][p] -> XT[n][p][c] (bf16) and gb[n][c][p] (bf16),
//      with fused fp32->bf16 weight conversion (first 768 flat blocks). ----
__global__ __launch_bounds__(256) void k_prep(const float* __restrict__ x,
                                              const float* __restrict__ tw,
                                              const float* __restrict__ pw,
                                              const float* __restrict__ cw,
                                              unsigned short* __restrict__ XT,
                                              unsigned short* __restrict__ gb,
                                              unsigned short* __restrict__ Wbt,
                                              unsigned short* __restrict__ Wbp,
                                              unsigned short* __restrict__ Wbc) {
    __shared__ float T[64][65];
    int fb = blockIdx.x + 64 * (blockIdx.y + 4 * blockIdx.z);
    if (fb < 768) {            // 768*256 = 196608 = 3 x 256x256 weights
        int i = fb * 256 + threadIdx.x;
        int sel = i >> 16, off = i & 65535;
        const float* s = sel == 0 ? tw : (sel == 1 ? pw : cw);
        unsigned short* d = sel == 0 ? Wbt : (sel == 1 ? Wbp : Wbc);
        d[off] = f2b(s[off]);
    }
    int n = blockIdx.z, c0 = blockIdx.y * 64, p0 = blockIdx.x * 64;
    int t = threadIdx.x;
    int pl = t & 63, rg = t >> 6;
    const float* xp = x + ((size_t)n * CC + c0) * HW + p0;
    #pragma unroll
    for (int i = 0; i < 16; i++) {
        int cl = rg * 16 + i;
        float v = xp[(size_t)cl * HW + pl];
        T[cl][pl] = v;
        gb[((size_t)n * CC + c0 + cl) * HW + p0 + pl] = f2b(v);
    }
    __syncthreads();
    int cl = t & 63, pg = t >> 6;
    unsigned short* xt = XT + ((size_t)n * HW + p0) * CC + c0;
    #pragma unroll
    for (int i = 0; i < 16; i++) {
        int plw = pg * 16 + i;
        xt[(size_t)plw * CC + cl] = f2b(T[cl][plw]);
    }
}

// ---- kernel 2: projection GEMM  outT[p][co] = sum_ci XT[p][ci]*W[co][ci] + b[co] ----
__global__ __launch_bounds__(256) void k_proj(const unsigned short* __restrict__ XT,
                                              const unsigned short* __restrict__ Wt,
                                              const unsigned short* __restrict__ Wp,
                                              const float* __restrict__ bt,
                                              const float* __restrict__ bp,
                                              unsigned short* __restrict__ outT_t,
                                              unsigned short* __restrict__ outT_p) {
    const unsigned short* W; const float* b; unsigned short* outT;
    if (blockIdx.y == 0) { W = Wt; b = bt; outT = outT_t; }
    else                 { W = Wp; b = bp; outT = outT_p; }
    int w = threadIdx.x >> 6, lane = threadIdx.x & 63;
    int nidx = lane & 15, quad = lane >> 4;
    size_t row0 = (size_t)blockIdx.x * 64 + w * 16;
    float4_t acc[16];
    #pragma unroll
    for (int i = 0; i < 16; i++) acc[i] = (float4_t)(0.f);
    const unsigned short* arow = XT + (row0 + nidx) * CC + quad * 8;
    for (int ks = 0; ks < 8; ks++) {
        short8 a = *(const short8*)(arow + ks * 32);
        #pragma unroll
        for (int cb = 0; cb < 16; cb++) {
            short8 bb = *(const short8*)(W + (size_t)(cb * 16 + nidx) * CC + ks * 32 + quad * 8);
            acc[cb] = __builtin_amdgcn_mfma_f32_16x16x32_bf16(a, bb, acc[cb], 0, 0, 0);
        }
    }
    #pragma unroll
    for (int cb = 0; cb < 16; cb++) {
        int co = cb * 16 + nidx;
        float bias = b[co];
        #pragma unroll
        for (int r = 0; r < 4; r++) {
            size_t prow = row0 + quad * 4 + r;
            outT[prow * CC + co] = f2b(acc[cb][r] + bias);
        }
    }
}

// ---- kernel 3: flash attention. Round-8: 32 queries/block, FULL 4096 keys,
// grid 512 -> 2 blocks/CU resident. Per-wave live set ~200 regs (th 64, o 32,
// kr/vr 64, pf 16) fits 2 waves/SIMD under the 256-reg boundary (m69) with NO
// occupancy attribute (r5/r6: caps cause spill/remat; r7: 64q tile = ~260 regs
// = 1 wave/SIMD). No key-split -> no partial O / k_reduce; direct fT output.
// QK^T role-swapped (A=K 16 keys of wave, B=theta 32q) -> S^T; P relayed
// fragment-major via LDS (conflict-free b128 streams); PV: A=V (wave's 64 ch),
// B=P. Single-buffered WAR-ordered K/V prefetch registers.
__global__ __launch_bounds__(256)
void k_attn(const unsigned short* __restrict__ thetaT,
            const unsigned short* __restrict__ phiT,
            const unsigned short* __restrict__ gb,
            unsigned short* __restrict__ fT) {
    __shared__ __align__(16) ushort Pbuf[2][4][64][8];   // [buf][frag(qt*2+kst)][lane][8] = 8 KB
    __shared__ __align__(16) ushort Obf[32][264];        // epilogue transpose, 16.5 KB
    __shared__ float Lbuf[4][32];

    const int tid = threadIdx.x;
    const int w = tid >> 6, lane = tid & 63;
    const int nidx = lane & 15, quad = lane >> 4;
    const int nb = (blockIdx.x & 7) >> 1;                // batch -> XCD pair
    const int tile = ((blockIdx.x >> 3) << 1) | (blockIdx.x & 1);  // 0..127
    const int p0 = tile * 32;
    const size_t seq0 = (size_t)nb * HW;
    const ushort* Kg = phiT + seq0 * CC;                 // [4096][256]
    const ushort* Vg = gb + (size_t)nb * CC * HW;        // [256][4096]

    // persistent theta B-frags for this block's 32 queries (64 VGPR)
    short8 th[2][8];
    #pragma unroll
    for (int qt = 0; qt < 2; qt++) {
        const ushort* qrow = thetaT + (seq0 + p0 + qt * 16 + nidx) * CC + quad * 8;
        #pragma unroll
        for (int kb = 0; kb < 8; kb++) th[qt][kb] = *(const short8*)(qrow + kb * 32);
    }

    float4_t o[4][2];
    #pragma unroll
    for (int i = 0; i < 4; i++)
        #pragma unroll
        for (int j = 0; j < 2; j++) o[i][j] = (float4_t)(0.f);
    float lrow[2] = {0.f, 0.f};

    const ushort* kbase = Kg + (size_t)(w * 16 + nidx) * CC + quad * 8;
    const float SC = 0.0625f * 1.44269504088896f;        // /sqrt(256) * log2(e)

    auto loadK = [&](short8 (&kr)[8], int t) {
        const ushort* p = kbase + (size_t)t * 64 * CC;
        #pragma unroll
        for (int kb = 0; kb < 8; kb++) kr[kb] = *(const short8*)(p + kb * 32);
    };
    auto loadV = [&](short8 (&vr)[8], int t) {
        #pragma unroll
        for (int ct = 0; ct < 4; ct++)
            #pragma unroll
            for (int kst = 0; kst < 2; kst++)
                vr[ct * 2 + kst] = *(const short8*)(Vg + (size_t)(w * 64 + ct * 16 + nidx) * HW
                                                    + t * 64 + kst * 32 + quad * 8);
    };
    // P write target: frag (qt, kst=w>>1), cell lane = ((w&1)*2+(quad>>1))*16+nidx,
    // ushort offset (quad&1)*4
    const int pfrag_k = w >> 1;
    const int pcell = ((w & 1) * 2 + (quad >> 1)) * 16 + nidx;
    const int poff = (quad & 1) * 4;

    short8 kr[8], vr[8];
    loadK(kr, 0); loadV(vr, 0);

    #pragma unroll 1
    for (int t = 0; t < 64; t++) {
        const int buf = t & 1;
        const int tn = (t + 1 < 64) ? t + 1 : 63;
        // ---- QK^T: S^T[16 keys of wave][32 q], 2 independent acc chains ----
        float4_t s0 = (float4_t)(0.f), s1 = (float4_t)(0.f);
        #pragma unroll
        for (int kb = 0; kb < 8; kb++) {
            s0 = __builtin_amdgcn_mfma_f32_16x16x32_bf16(kr[kb], th[0][kb], s0, 0, 0, 0);
            s1 = __builtin_amdgcn_mfma_f32_16x16x32_bf16(kr[kb], th[1][kb], s1, 0, 0, 0);
        }
        loadK(kr, tn);       // WAR-safe: QK(t) consumed kr; lands during exp+PV
        // ---- exp, row-sum partials, pack to P relay (fragment-major) ----
        {
            float e0 = exp2f(s0[0] * SC), e1 = exp2f(s0[1] * SC);
            float e2 = exp2f(s0[2] * SC), e3 = exp2f(s0[3] * SC);
            lrow[0] += e0 + e1 + e2 + e3;
            short4_t pk = { (short)f2b(e0), (short)f2b(e1), (short)f2b(e2), (short)f2b(e3) };
            *(short4_t*)(&Pbuf[buf][0 * 2 + pfrag_k][pcell][poff]) = pk;
        }
        {
            float e0 = exp2f(s1[0] * SC), e1 = exp2f(s1[1] * SC);
            float e2 = exp2f(s1[2] * SC), e3 = exp2f(s1[3] * SC);
            lrow[1] += e0 + e1 + e2 + e3;
            short4_t pk = { (short)f2b(e0), (short)f2b(e1), (short)f2b(e2), (short)f2b(e3) };
            *(short4_t*)(&Pbuf[buf][1 * 2 + pfrag_k][pcell][poff]) = pk;
        }
        __syncthreads();                                  // P(t) complete
        // ---- PV: o[ch 64 of wave][q 32] += V * P ----
        short8 pf[4];
        #pragma unroll
        for (int f = 0; f < 4; f++)
            pf[f] = *(const short8*)(&Pbuf[buf][f][lane][0]);
        #pragma unroll
        for (int ct = 0; ct < 4; ct++)
            #pragma unroll
            for (int qt = 0; qt < 2; qt++)
                #pragma unroll
                for (int kst = 0; kst < 2; kst++)
                    o[ct][qt] = __builtin_amdgcn_mfma_f32_16x16x32_bf16(
                        vr[ct * 2 + kst], pf[qt * 2 + kst], o[ct][qt], 0, 0, 0);
        loadV(vr, tn);       // WAR-safe: PV(t) consumed vr; lands during next QK+exp
    }

    // ---- epilogue: reduce l across quads + waves, normalize, store ----
    #pragma unroll
    for (int qt = 0; qt < 2; qt++) {
        float v = lrow[qt];
        v += __shfl_xor(v, 16);
        v += __shfl_xor(v, 32);
        if (quad == 0) Lbuf[w][qt * 16 + nidx] = v;
    }
    __syncthreads();
    float linv[2];
    #pragma unroll
    for (int qt = 0; qt < 2; qt++) {
        int q = qt * 16 + nidx;
        linv[qt] = 1.0f / (Lbuf[0][q] + Lbuf[1][q] + Lbuf[2][q] + Lbuf[3][q]);
    }
    // lane holds O[ch = w*64+ct*16+quad*4+r][q = qt*16+nidx]
    #pragma unroll
    for (int ct = 0; ct < 4; ct++)
        #pragma unroll
        for (int qt = 0; qt < 2; qt++) {
            short4_t pk;
            #pragma unroll
            for (int r = 0; r < 4; r++) pk[r] = (short)f2b(o[ct][qt][r] * linv[qt]);
            *(short4_t*)(&Obf[qt * 16 + nidx][w * 64 + ct * 16 + quad * 4]) = pk;
        }
    __syncthreads();
    ushort* dst = fT + (seq0 + p0) * CC;
    #pragma unroll
    for (int i = 0; i < 4; i++) {
        int c = i * 256 + tid;                            // 1024 b128 chunks total
        int q = c >> 5, cc = (c & 31) * 8;
        *(short8*)(dst + (size_t)q * CC + cc) = *(const short8*)(&Obf[q][cc]);
    }
}

// ---- kernel 4: out[n][co][p] = x + b[co] + sum_k W[co][k]*fT[p][k] ----
__global__ __launch_bounds__(256) void k_final(const unsigned short* __restrict__ Wc,
                                               const float* __restrict__ bc,
                                               const unsigned short* __restrict__ fT,
                                               const float* __restrict__ x,
                                               float* __restrict__ out) {
    int w = threadIdx.x >> 6, lane = threadIdx.x & 63;
    int nidx = lane & 15, quad = lane >> 4;
    int n = blockIdx.z;
    int co0 = blockIdx.y * 64 + w * 16;
    int p0 = blockIdx.x * 64;
    float4_t acc[4];
    #pragma unroll
    for (int i = 0; i < 4; i++) acc[i] = (float4_t)(0.f);
    const unsigned short* arow = Wc + (size_t)(co0 + nidx) * CC + quad * 8;
    const unsigned short* brow = fT + ((size_t)n * HW + p0 + nidx) * CC + quad * 8;
    for (int ks = 0; ks < 8; ks++) {
        short8 a = *(const short8*)(arow + ks * 32);
        #pragma unroll
        for (int pb = 0; pb < 4; pb++) {
            short8 bb = *(const short8*)(brow + (size_t)pb * 16 * CC + ks * 32);
            acc[pb] = __builtin_amdgcn_mfma_f32_16x16x32_bf16(a, bb, acc[pb], 0, 0, 0);
        }
    }
    #pragma unroll
    for (int pb = 0; pb < 4; pb++) {
        #pragma unroll
        for (int r = 0; r < 4; r++) {
            int co = co0 + quad * 4 + r;
            size_t idx = ((size_t)n * CC + co) * HW + p0 + pb * 16 + nidx;
            out[idx] = x[idx] + bc[co] + acc[pb][r];
        }
    }
}

extern "C" void kernel_launch(void* const* d_in, const int* in_sizes, int n_in,
                              void* d_out, int out_size, void* d_ws, size_t ws_size,
                              hipStream_t stream) {
    const float* x       = (const float*)d_in[0];
    const float* theta_w = (const float*)d_in[1];
    const float* theta_b = (const float*)d_in[2];
    const float* phi_w   = (const float*)d_in[3];
    const float* phi_b   = (const float*)d_in[4];
    const float* conv1_w = (const float*)d_in[5];
    const float* conv1_b = (const float*)d_in[6];
    float* out = (float*)d_out;

    unsigned short* XT  = (unsigned short*)d_ws;  // [SEQ][256] bf16
    unsigned short* gb  = XT  + SEQ * CC;         // [N][256][4096]
    unsigned short* thT = gb  + SEQ * CC;         // [SEQ][256]
    unsigned short* phT = thT + SEQ * CC;         // [SEQ][256]
    unsigned short* fT  = phT + SEQ * CC;         // [SEQ][256]
    unsigned short* Wbt = fT  + SEQ * CC;
    unsigned short* Wbp = Wbt + 65536;
    unsigned short* Wbc = Wbp + 65536;

    k_prep<<<dim3(64, 4, 4), 256, 0, stream>>>(x, theta_w, phi_w, conv1_w, XT, gb, Wbt, Wbp, Wbc);
    k_proj<<<dim3(256, 2), 256, 0, stream>>>(XT, Wbt, Wbp, theta_b, phi_b, thT, phT);
    k_attn<<<dim3(512), 256, 0, stream>>>(thT, phT, gb, fT);
    k_final<<<dim3(64, 4, 4), 256, 0, stream>>>(Wbc, conv1_b, fT, x, out);
}

// Round 9
// 231.961 us; speedup vs baseline: 1.5859x; 1.5859x over previous
//
#include <hip/hip_runtime.h>
#include <hip/hip_bf16.h>

typedef __attribute__((ext_vector_type(8))) short short8;
typedef __attribute__((ext_vector_type(4))) short short4_t;
typedef __attribute__((ext_vector_type(4))) float float4_t;
typedef unsigned short ushort;

#define HW 4096
#define CC 256
#define NBATCH 4
#define SEQ ((size_t)NBATCH * HW)

static __device__ __forceinline__ unsigned short f2b(float f) {
    union { float f; unsigned u; } v; v.f = f;
    unsigned r = v.u + 0x7FFF + ((v.u >> 16) & 1);   // RNE
    return (unsigned short)(r >> 16);
}

// ---- kernel 1: x[n][c][p] -> XT[n][p][c] (bf16) and gb[n][c][p] (bf16),
//      with fused fp32->bf16 weight conversion (first 768 flat blocks). ----
__global__ __launch_bounds__(256) void k_prep(const float* __restrict__ x,
                                              const float* __restrict__ tw,
                                              const float* __restrict__ pw,
                                              const float* __restrict__ cw,
                                              unsigned short* __restrict__ XT,
                                              unsigned short* __restrict__ gb,
                                              unsigned short* __restrict__ Wbt,
                                              unsigned short* __restrict__ Wbp,
                                              unsigned short* __restrict__ Wbc) {
    __shared__ float T[64][65];
    int fb = blockIdx.x + 64 * (blockIdx.y + 4 * blockIdx.z);
    if (fb < 768) {            // 768*256 = 196608 = 3 x 256x256 weights
        int i = fb * 256 + threadIdx.x;
        int sel = i >> 16, off = i & 65535;
        const float* s = sel == 0 ? tw : (sel == 1 ? pw : cw);
        unsigned short* d = sel == 0 ? Wbt : (sel == 1 ? Wbp : Wbc);
        d[off] = f2b(s[off]);
    }
    int n = blockIdx.z, c0 = blockIdx.y * 64, p0 = blockIdx.x * 64;
    int t = threadIdx.x;
    int pl = t & 63, rg = t >> 6;
    const float* xp = x + ((size_t)n * CC + c0) * HW + p0;
    #pragma unroll
    for (int i = 0; i < 16; i++) {
        int cl = rg * 16 + i;
        float v = xp[(size_t)cl * HW + pl];
        T[cl][pl] = v;
        gb[((size_t)n * CC + c0 + cl) * HW + p0 + pl] = f2b(v);
    }
    __syncthreads();
    int cl = t & 63, pg = t >> 6;
    unsigned short* xt = XT + ((size_t)n * HW + p0) * CC + c0;
    #pragma unroll
    for (int i = 0; i < 16; i++) {
        int plw = pg * 16 + i;
        xt[(size_t)plw * CC + cl] = f2b(T[cl][plw]);
    }
}

// ---- kernel 2: projection GEMM  outT[p][co] = sum_ci XT[p][ci]*W[co][ci] + b[co] ----
__global__ __launch_bounds__(256) void k_proj(const unsigned short* __restrict__ XT,
                                              const unsigned short* __restrict__ Wt,
                                              const unsigned short* __restrict__ Wp,
                                              const float* __restrict__ bt,
                                              const float* __restrict__ bp,
                                              unsigned short* __restrict__ outT_t,
                                              unsigned short* __restrict__ outT_p) {
    const unsigned short* W; const float* b; unsigned short* outT;
    if (blockIdx.y == 0) { W = Wt; b = bt; outT = outT_t; }
    else                 { W = Wp; b = bp; outT = outT_p; }
    int w = threadIdx.x >> 6, lane = threadIdx.x & 63;
    int nidx = lane & 15, quad = lane >> 4;
    size_t row0 = (size_t)blockIdx.x * 64 + w * 16;
    float4_t acc[16];
    #pragma unroll
    for (int i = 0; i < 16; i++) acc[i] = (float4_t)(0.f);
    const unsigned short* arow = XT + (row0 + nidx) * CC + quad * 8;
    for (int ks = 0; ks < 8; ks++) {
        short8 a = *(const short8*)(arow + ks * 32);
        #pragma unroll
        for (int cb = 0; cb < 16; cb++) {
            short8 bb = *(const short8*)(W + (size_t)(cb * 16 + nidx) * CC + ks * 32 + quad * 8);
            acc[cb] = __builtin_amdgcn_mfma_f32_16x16x32_bf16(a, bb, acc[cb], 0, 0, 0);
        }
    }
    #pragma unroll
    for (int cb = 0; cb < 16; cb++) {
        int co = cb * 16 + nidx;
        float bias = b[co];
        #pragma unroll
        for (int r = 0; r < 4; r++) {
            size_t prow = row0 + quad * 4 + r;
            outT[prow * CC + co] = f2b(acc[cb][r] + bias);
        }
    }
}

// ---- kernel 3 (round-9): flash attention, Q=128/block, 512 thr (8 waves),
// key-split 2 -> grid 256, 1 block/CU, 2 waves/SIMD.
// Evidence (r2/r4/r7/r8): k_attn is bound by ~12 B/cyc/CU L2 streaming; time ~
// traffic. Q=128 halves device traffic (each block's K/V range amortized over
// 2x queries). QK: A=theta (wave's 16 q, 32 persistent VGPR), B=K-frags from
// fragment-major LDS (staged once per tile, shared by all 8 waves; reads are
// lane*16 conflict-free streams). PV: wave owns 32 channels, A=V direct global
// b128 (no replication), B=P via fragment-major LDS relay. K & P double-
// buffered -> ONE barrier/tile. Outputs unnormalized fp32 partial O + l.
__global__ __launch_bounds__(512)
void k_attn(const unsigned short* __restrict__ thetaT,
            const unsigned short* __restrict__ phiT,
            const unsigned short* __restrict__ gb,
            float* __restrict__ Ow, float* __restrict__ lw) {
    __shared__ __align__(16) ushort Kl[2][16384];        // frag-major: [(ng*8+kb)*64+lane][8], 64 KB
    __shared__ __align__(16) ushort Pbuf[2][16][64][8];  // frag-major: [qg*2+kst][lane][8], 32 KB

    const int tid = threadIdx.x;
    const int w = tid >> 6, lane = tid & 63;
    const int nidx = lane & 15, quad = lane >> 4;
    const int nb = (blockIdx.x & 7) >> 1;                // batch -> XCD pair
    const int h  = blockIdx.x & 1;                       // key half
    const int qtile = blockIdx.x >> 3;                   // 0..31
    const int p0 = qtile * 128;
    const size_t seq0 = (size_t)nb * HW;
    const ushort* Kg = phiT + seq0 * CC;                 // [4096][256]
    const ushort* Vg = gb + (size_t)nb * CC * HW;        // [256][4096]
    const int k00 = h * 2048;

    // persistent theta A-frags: wave's 16 queries [p0 + w*16 .. +16)
    short8 th[8];
    {
        const ushort* qrow = thetaT + (seq0 + p0 + w * 16 + nidx) * CC + quad * 8;
        #pragma unroll
        for (int kb = 0; kb < 8; kb++) th[kb] = *(const short8*)(qrow + kb * 32);
    }

    float4_t o[2][8];                                    // o[mg][qg]: ch=w*32+mg*16+quad*4+r, q=qg*16+nidx
    #pragma unroll
    for (int i = 0; i < 2; i++)
        #pragma unroll
        for (int j = 0; j < 8; j++) o[i][j] = (float4_t)(0.f);
    float lrow[4] = {0.f, 0.f, 0.f, 0.f};

    // K staging geometry: thread handles chunk c = tid&31 (16B of a 512B key row),
    // key row = rr*16 + (tid>>5) per round rr. Frag-major dst is conflict-heavy on
    // write (32 KB/tile) but conflict-FREE on read (256 KB/tile) - the right trade.
    const int c_s = tid & 31, ns_s = tid >> 5;
    const int kfbase = (((c_s >> 2)) * 64 + (c_s & 3) * 16 + ns_s) * 8;
    auto loadKregs = [&](short8 (&kr)[4], int tt) {
        #pragma unroll
        for (int rr = 0; rr < 4; rr++)
            kr[rr] = *(const short8*)(Kg + (size_t)(k00 + tt * 64 + rr * 16 + ns_s) * CC + c_s * 8);
    };
    // V A-frags for wave's 32 channels (2 m-groups), tile t
    auto loadVregs = [&](short8 (&vr)[4], int tt) {
        #pragma unroll
        for (int mg = 0; mg < 2; mg++)
            #pragma unroll
            for (int kst = 0; kst < 2; kst++)
                vr[mg * 2 + kst] = *(const short8*)(Vg + (size_t)(w * 32 + mg * 16 + nidx) * HW
                                                    + k00 + tt * 64 + kst * 32 + quad * 8);
    };

    const float SC = 0.0625f * 1.44269504088896f;        // /sqrt(256) * log2(e)
    const int pj = nidx & 7;                             // P-write element
    const int pc_hi = (nidx >> 3);                       // P-write cell bits

    short8 kregs[4], vregs[4];
    // ---- prologue: stage tile 0, prefetch tile 1 ----
    loadKregs(kregs, 0);
    loadVregs(vregs, 0);
    #pragma unroll
    for (int rr = 0; rr < 4; rr++) *(short8*)(&Kl[0][rr * 4096 + kfbase]) = kregs[rr];
    loadKregs(kregs, 1);
    __syncthreads();                                     // Kl[0] ready

    #pragma unroll 1
    for (int t = 0; t < 32; t++) {
        const int b = t & 1;
        // ---- QK^T: S[16 q of wave][64 keys] = 4 n-group accs ----
        float4_t s0 = (float4_t)(0.f), s1 = (float4_t)(0.f);
        float4_t s2 = (float4_t)(0.f), s3 = (float4_t)(0.f);
        #pragma unroll
        for (int kb = 0; kb < 8; kb++) {
            short8 k0 = *(const short8*)(&Kl[b][(0 * 8 + kb) * 512 + lane * 8]);
            short8 k1 = *(const short8*)(&Kl[b][(1 * 8 + kb) * 512 + lane * 8]);
            short8 k2 = *(const short8*)(&Kl[b][(2 * 8 + kb) * 512 + lane * 8]);
            short8 k3 = *(const short8*)(&Kl[b][(3 * 8 + kb) * 512 + lane * 8]);
            s0 = __builtin_amdgcn_mfma_f32_16x16x32_bf16(th[kb], k0, s0, 0, 0, 0);
            s1 = __builtin_amdgcn_mfma_f32_16x16x32_bf16(th[kb], k1, s1, 0, 0, 0);
            s2 = __builtin_amdgcn_mfma_f32_16x16x32_bf16(th[kb], k2, s2, 0, 0, 0);
            s3 = __builtin_amdgcn_mfma_f32_16x16x32_bf16(th[kb], k3, s3, 0, 0, 0);
        }
        // ---- exp -> P relay (frag-major) + row-sum partials ----
        // value (q = w*16+quad*4+r, key = ng*16+nidx) -> frag(qg=w, kst=ng>>1),
        // cell = ((ng&1)*2 + nidx>>3)*16 + quad*4 + r, elem j = nidx&7
        {
            #pragma unroll
            for (int r = 0; r < 4; r++) {
                float e = exp2f(s0[r] * SC); lrow[r] += e;
                Pbuf[b][w * 2 + 0][(0 * 2 + pc_hi) * 16 + quad * 4 + r][pj] = f2b(e);
            }
            #pragma unroll
            for (int r = 0; r < 4; r++) {
                float e = exp2f(s1[r] * SC); lrow[r] += e;
                Pbuf[b][w * 2 + 0][(1 * 2 + pc_hi) * 16 + quad * 4 + r][pj] = f2b(e);
            }
            #pragma unroll
            for (int r = 0; r < 4; r++) {
                float e = exp2f(s2[r] * SC); lrow[r] += e;
                Pbuf[b][w * 2 + 1][(0 * 2 + pc_hi) * 16 + quad * 4 + r][pj] = f2b(e);
            }
            #pragma unroll
            for (int r = 0; r < 4; r++) {
                float e = exp2f(s3[r] * SC); lrow[r] += e;
                Pbuf[b][w * 2 + 1][(1 * 2 + pc_hi) * 16 + quad * 4 + r][pj] = f2b(e);
            }
        }
        // ---- stage K(t+1) into Kl[b^1] (regs prefetched last iter), prefetch K(t+2) ----
        if (t < 31) {
            #pragma unroll
            for (int rr = 0; rr < 4; rr++) *(short8*)(&Kl[b ^ 1][rr * 4096 + kfbase]) = kregs[rr];
            const int tn2 = (t + 2 < 32) ? t + 2 : 31;
            loadKregs(kregs, tn2);
        }
        __syncthreads();                                 // P(t) + Kl[t+1] ready
        // ---- PV: o[wave's 32 ch][128 q] += V * P ----
        #pragma unroll
        for (int qg = 0; qg < 8; qg++) {
            short8 pf0 = *(const short8*)(&Pbuf[b][qg * 2 + 0][lane][0]);
            short8 pf1 = *(const short8*)(&Pbuf[b][qg * 2 + 1][lane][0]);
            o[0][qg] = __builtin_amdgcn_mfma_f32_16x16x32_bf16(vregs[0], pf0, o[0][qg], 0, 0, 0);
            o[0][qg] = __builtin_amdgcn_mfma_f32_16x16x32_bf16(vregs[1], pf1, o[0][qg], 0, 0, 0);
            o[1][qg] = __builtin_amdgcn_mfma_f32_16x16x32_bf16(vregs[2], pf0, o[1][qg], 0, 0, 0);
            o[1][qg] = __builtin_amdgcn_mfma_f32_16x16x32_bf16(vregs[3], pf1, o[1][qg], 0, 0, 0);
        }
        loadVregs(vregs, (t + 1 < 32) ? t + 1 : 31);     // WAR-safe: PV consumed vregs
    }

    // ---- epilogue: partial l (reduce over keys across nidx), partial O stores ----
    #pragma unroll
    for (int r = 0; r < 4; r++) {
        float v = lrow[r];
        v += __shfl_xor(v, 1);
        v += __shfl_xor(v, 2);
        v += __shfl_xor(v, 4);
        v += __shfl_xor(v, 8);
        if (nidx == 0)
            lw[(size_t)h * SEQ + seq0 + p0 + w * 16 + quad * 4 + r] = v;
    }
    float* Op = Ow + ((size_t)h * SEQ + seq0 + p0) * CC;
    #pragma unroll
    for (int mg = 0; mg < 2; mg++)
        #pragma unroll
        for (int qg = 0; qg < 8; qg++)
            *(float4_t*)(Op + (size_t)(qg * 16 + nidx) * CC + w * 32 + mg * 16 + quad * 4) = o[mg][qg];
}

// ---- kernel 3b: combine key-halves: fT[q][ch] = (O0+O1)/(l0+l1) as bf16 ----
__global__ __launch_bounds__(256) void k_reduce(const float* __restrict__ Ow,
                                                const float* __restrict__ lw,
                                                unsigned short* __restrict__ fT) {
    const float4_t* O0 = (const float4_t*)Ow;
    const float4_t* O1 = (const float4_t*)(Ow + SEQ * CC);
    int i0 = blockIdx.x * 256 + threadIdx.x;             // grid 1024 x 4 iters
    #pragma unroll
    for (int j = 0; j < 4; j++) {
        int idx = j * 262144 + i0;                       // float4 index, SEQ*CC/4 total
        int row = idx >> 6;                              // 64 float4 per 256-ch row
        float li = 1.0f / (lw[row] + lw[SEQ + row]);
        float4_t a = O0[idx];
        float4_t b = O1[idx];
        short4_t pk;
        #pragma unroll
        for (int r = 0; r < 4; r++) pk[r] = (short)f2b((a[r] + b[r]) * li);
        *(short4_t*)(fT + (size_t)idx * 4) = pk;
    }
}

// ---- kernel 4: out[n][co][p] = x + b[co] + sum_k W[co][k]*fT[p][k] ----
__global__ __launch_bounds__(256) void k_final(const unsigned short* __restrict__ Wc,
                                               const float* __restrict__ bc,
                                               const unsigned short* __restrict__ fT,
                                               const float* __restrict__ x,
                                               float* __restrict__ out) {
    int w = threadIdx.x >> 6, lane = threadIdx.x & 63;
    int nidx = lane & 15, quad = lane >> 4;
    int n = blockIdx.z;
    int co0 = blockIdx.y * 64 + w * 16;
    int p0 = blockIdx.x * 64;
    float4_t acc[4];
    #pragma unroll
    for (int i = 0; i < 4; i++) acc[i] = (float4_t)(0.f);
    const unsigned short* arow = Wc + (size_t)(co0 + nidx) * CC + quad * 8;
    const unsigned short* brow = fT + ((size_t)n * HW + p0 + nidx) * CC + quad * 8;
    for (int ks = 0; ks < 8; ks++) {
        short8 a = *(const short8*)(arow + ks * 32);
        #pragma unroll
        for (int pb = 0; pb < 4; pb++) {
            short8 bb = *(const short8*)(brow + (size_t)pb * 16 * CC + ks * 32);
            acc[pb] = __builtin_amdgcn_mfma_f32_16x16x32_bf16(a, bb, acc[pb], 0, 0, 0);
        }
    }
    #pragma unroll
    for (int pb = 0; pb < 4; pb++) {
        #pragma unroll
        for (int r = 0; r < 4; r++) {
            int co = co0 + quad * 4 + r;
            size_t idx = ((size_t)n * CC + co) * HW + p0 + pb * 16 + nidx;
            out[idx] = x[idx] + bc[co] + acc[pb][r];
        }
    }
}

extern "C" void kernel_launch(void* const* d_in, const int* in_sizes, int n_in,
                              void* d_out, int out_size, void* d_ws, size_t ws_size,
                              hipStream_t stream) {
    const float* x       = (const float*)d_in[0];
    const float* theta_w = (const float*)d_in[1];
    const float* theta_b = (const float*)d_in[2];
    const float* phi_w   = (const float*)d_in[3];
    const float* phi_b   = (const float*)d_in[4];
    const float* conv1_w = (const float*)d_in[5];
    const float* conv1_b = (const float*)d_in[6];
    float* out = (float*)d_out;

    unsigned short* XT  = (unsigned short*)d_ws;  // [SEQ][256] bf16
    unsigned short* gb  = XT  + SEQ * CC;         // [N][256][4096]
    unsigned short* thT = gb  + SEQ * CC;         // [SEQ][256]
    unsigned short* phT = thT + SEQ * CC;         // [SEQ][256]
    unsigned short* fT  = phT + SEQ * CC;         // [SEQ][256]
    unsigned short* Wbt = fT  + SEQ * CC;
    unsigned short* Wbp = Wbt + 65536;
    unsigned short* Wbc = Wbp + 65536;
    float* Ow = (float*)(Wbc + 65536);            // [2][SEQ][256] fp32 partial O
    float* lw = Ow + 2 * SEQ * CC;                // [2][SEQ] fp32 partial l

    k_prep<<<dim3(64, 4, 4), 256, 0, stream>>>(x, theta_w, phi_w, conv1_w, XT, gb, Wbt, Wbp, Wbc);
    k_proj<<<dim3(256, 2), 256, 0, stream>>>(XT, Wbt, Wbp, theta_b, phi_b, thT, phT);
    k_attn<<<dim3(256), 512, 0, stream>>>(thT, phT, gb, Ow, lw);
    k_reduce<<<dim3(1024), 256, 0, stream>>>(Ow, lw, fT);
    k_final<<<dim3(64, 4, 4), 256, 0, stream>>>(Wbc, conv1_b, fT, x, out);
}

// Round 10
// 222.085 us; speedup vs baseline: 1.6564x; 1.0445x over previous
//
#include <hip/hip_runtime.h>
#include <hip/hip_bf16.h>

typedef __attribute__((ext_vector_type(8))) short short8;
typedef __attribute__((ext_vector_type(4))) short short4_t;
typedef __attribute__((ext_vector_type(4))) float float4_t;
typedef unsigned short ushort;

#define HW 4096
#define CC 256
#define NBATCH 4
#define SEQ ((size_t)NBATCH * HW)

static __device__ __forceinline__ unsigned short f2b(float f) {
    union { float f; unsigned u; } v; v.f = f;
    unsigned r = v.u + 0x7FFF + ((v.u >> 16) & 1);   // RNE
    return (unsigned short)(r >> 16);
}

// ---- kernel 1: x[n][c][p] -> XT[n][p][c] (bf16) and gb[n][c][p] (bf16),
//      with fused fp32->bf16 weight conversion (first 768 flat blocks). ----
__global__ __launch_bounds__(256) void k_prep(const float* __restrict__ x,
                                              const float* __restrict__ tw,
                                              const float* __restrict__ pw,
                                              const float* __restrict__ cw,
                                              unsigned short* __restrict__ XT,
                                              unsigned short* __restrict__ gb,
                                              unsigned short* __restrict__ Wbt,
                                              unsigned short* __restrict__ Wbp,
                                              unsigned short* __restrict__ Wbc) {
    __shared__ float T[64][65];
    int fb = blockIdx.x + 64 * (blockIdx.y + 4 * blockIdx.z);
    if (fb < 768) {            // 768*256 = 196608 = 3 x 256x256 weights
        int i = fb * 256 + threadIdx.x;
        int sel = i >> 16, off = i & 65535;
        const float* s = sel == 0 ? tw : (sel == 1 ? pw : cw);
        unsigned short* d = sel == 0 ? Wbt : (sel == 1 ? Wbp : Wbc);
        d[off] = f2b(s[off]);
    }
    int n = blockIdx.z, c0 = blockIdx.y * 64, p0 = blockIdx.x * 64;
    int t = threadIdx.x;
    int pl = t & 63, rg = t >> 6;
    const float* xp = x + ((size_t)n * CC + c0) * HW + p0;
    #pragma unroll
    for (int i = 0; i < 16; i++) {
        int cl = rg * 16 + i;
        float v = xp[(size_t)cl * HW + pl];
        T[cl][pl] = v;
        gb[((size_t)n * CC + c0 + cl) * HW + p0 + pl] = f2b(v);
    }
    __syncthreads();
    int cl = t & 63, pg = t >> 6;
    unsigned short* xt = XT + ((size_t)n * HW + p0) * CC + c0;
    #pragma unroll
    for (int i = 0; i < 16; i++) {
        int plw = pg * 16 + i;
        xt[(size_t)plw * CC + cl] = f2b(T[cl][plw]);
    }
}

// ---- kernel 2: projection GEMM  outT[p][co] = sum_ci XT[p][ci]*W[co][ci] + b[co] ----
__global__ __launch_bounds__(256) void k_proj(const unsigned short* __restrict__ XT,
                                              const unsigned short* __restrict__ Wt,
                                              const unsigned short* __restrict__ Wp,
                                              const float* __restrict__ bt,
                                              const float* __restrict__ bp,
                                              unsigned short* __restrict__ outT_t,
                                              unsigned short* __restrict__ outT_p) {
    const unsigned short* W; const float* b; unsigned short* outT;
    if (blockIdx.y == 0) { W = Wt; b = bt; outT = outT_t; }
    else                 { W = Wp; b = bp; outT = outT_p; }
    int w = threadIdx.x >> 6, lane = threadIdx.x & 63;
    int nidx = lane & 15, quad = lane >> 4;
    size_t row0 = (size_t)blockIdx.x * 64 + w * 16;
    float4_t acc[16];
    #pragma unroll
    for (int i = 0; i < 16; i++) acc[i] = (float4_t)(0.f);
    const unsigned short* arow = XT + (row0 + nidx) * CC + quad * 8;
    for (int ks = 0; ks < 8; ks++) {
        short8 a = *(const short8*)(arow + ks * 32);
        #pragma unroll
        for (int cb = 0; cb < 16; cb++) {
            short8 bb = *(const short8*)(W + (size_t)(cb * 16 + nidx) * CC + ks * 32 + quad * 8);
            acc[cb] = __builtin_amdgcn_mfma_f32_16x16x32_bf16(a, bb, acc[cb], 0, 0, 0);
        }
    }
    #pragma unroll
    for (int cb = 0; cb < 16; cb++) {
        int co = cb * 16 + nidx;
        float bias = b[co];
        #pragma unroll
        for (int r = 0; r < 4; r++) {
            size_t prow = row0 + quad * 4 + r;
            outT[prow * CC + co] = f2b(acc[cb][r] + bias);
        }
    }
}

// ---- kernel 3 (round-10): flash attention, Q=128/block, 512 thr (8 waves),
// key-split 2 -> grid 256. r9 counters: LDS is the binding pipe (432 KB/tile/CU
// = 108k cyc issue floor + 65k conflict cycles from 32-way K-staging writes).
// Changes vs r9:
//  (1) QK key-split across wave pairs: wave w = (qg=w&3: 32 q, kh=w>>2: 32 of
//      64 keys). theta doubles to 32q/wave (64 VGPR) but each wave reads only
//      HALF the K tile (16 KB) -> LDS/tile 432 -> 304 KB.
//  (2) Conflict-free K staging: thread -> (key n=tid&15, chunk c=tid>>4) makes
//      write cells (c&3)*16+n span all 32 banks (was: all lanes on one 16B
//      column, 32-way conflict). Global reads stay full-line coalesced.
// PV (ch-split, V direct global, P relay frag-major) and barrier structure
// unchanged. Outputs unnormalized fp32 partial O + l per key-half.
__global__ __launch_bounds__(512)
void k_attn(const unsigned short* __restrict__ thetaT,
            const unsigned short* __restrict__ phiT,
            const unsigned short* __restrict__ gb,
            float* __restrict__ Ow, float* __restrict__ lw) {
    __shared__ __align__(16) ushort Kl[2][16384];        // frag-major: [(ng*8+kb)*64+cell][8], 64 KB
    __shared__ __align__(16) ushort Pbuf[2][16][64][8];  // frag-major: [qg*2+kst][cell][8], 32 KB
    __shared__ float Lbuf[2][128];

    const int tid = threadIdx.x;
    const int w = tid >> 6, lane = tid & 63;
    const int nidx = lane & 15, quad = lane >> 4;
    const int qg = w & 3;                                // q-group (32 q) for QK
    const int kh = w >> 2;                               // key-half (32 keys) for QK
    const int nb = (blockIdx.x & 7) >> 1;                // batch -> XCD pair
    const int h  = blockIdx.x & 1;                       // key half (kernel-level split)
    const int qtile = blockIdx.x >> 3;                   // 0..31
    const int p0 = qtile * 128;
    const size_t seq0 = (size_t)nb * HW;
    const ushort* Kg = phiT + seq0 * CC;                 // [4096][256]
    const ushort* Vg = gb + (size_t)nb * CC * HW;        // [256][4096]
    const int k00 = h * 2048;

    // persistent theta A-frags: wave's 32 queries [p0 + qg*32 .. +32)
    short8 th[2][8];
    #pragma unroll
    for (int qs = 0; qs < 2; qs++) {
        const ushort* qrow = thetaT + (seq0 + p0 + qg * 32 + qs * 16 + nidx) * CC + quad * 8;
        #pragma unroll
        for (int kb = 0; kb < 8; kb++) th[qs][kb] = *(const short8*)(qrow + kb * 32);
    }

    float4_t o[2][8];                                    // o[mg][qq]: ch=w*32+mg*16+quad*4+r, q=qq*16+nidx
    #pragma unroll
    for (int i = 0; i < 2; i++)
        #pragma unroll
        for (int j = 0; j < 8; j++) o[i][j] = (float4_t)(0.f);
    float lrow[8];
    #pragma unroll
    for (int i = 0; i < 8; i++) lrow[i] = 0.f;

    // K staging: thread -> key offset n_s = tid&15 (of 16 per round rr), chunk
    // c_s = tid>>4 (16B of the 512B key row). Write cell = (c_s&3)*16 + n_s
    // spans banks uniformly; global reads are 16 full 64B lines per wave instr.
    const int c_s = tid >> 4, n_s = tid & 15;
    const int kfbase = (c_s >> 2) * 512 + ((c_s & 3) * 16 + n_s) * 8;
    auto loadKregs = [&](short8 (&kr)[4], int tt) {
        #pragma unroll
        for (int rr = 0; rr < 4; rr++)
            kr[rr] = *(const short8*)(Kg + (size_t)(k00 + tt * 64 + rr * 16 + n_s) * CC + c_s * 8);
    };
    // V A-frags for wave's 32 channels (2 m-groups), tile t
    auto loadVregs = [&](short8 (&vr)[4], int tt) {
        #pragma unroll
        for (int mg = 0; mg < 2; mg++)
            #pragma unroll
            for (int kst = 0; kst < 2; kst++)
                vr[mg * 2 + kst] = *(const short8*)(Vg + (size_t)(w * 32 + mg * 16 + nidx) * HW
                                                    + k00 + tt * 64 + kst * 32 + quad * 8);
    };

    const float SC = 0.0625f * 1.44269504088896f;        // /sqrt(256) * log2(e)
    const int pj = nidx & 7;                             // P-write element
    const int pc_hi = nidx >> 3;                         // P-write cell bit

    short8 kregs[4], vregs[4];
    // ---- prologue: stage tile 0, prefetch tile 1 ----
    loadKregs(kregs, 0);
    loadVregs(vregs, 0);
    #pragma unroll
    for (int rr = 0; rr < 4; rr++) *(short8*)(&Kl[0][rr * 4096 + kfbase]) = kregs[rr];
    loadKregs(kregs, 1);
    __syncthreads();                                     // Kl[0] ready

    #pragma unroll 1
    for (int t = 0; t < 32; t++) {
        const int b = t & 1;
        // ---- QK^T: S[32 q of wave][32 keys of wave's half] = 4 accs ----
        float4_t s00 = (float4_t)(0.f), s01 = (float4_t)(0.f);
        float4_t s10 = (float4_t)(0.f), s11 = (float4_t)(0.f);
        #pragma unroll
        for (int kb = 0; kb < 8; kb++) {
            short8 k0 = *(const short8*)(&Kl[b][((kh * 2 + 0) * 8 + kb) * 512 + lane * 8]);
            short8 k1 = *(const short8*)(&Kl[b][((kh * 2 + 1) * 8 + kb) * 512 + lane * 8]);
            s00 = __builtin_amdgcn_mfma_f32_16x16x32_bf16(th[0][kb], k0, s00, 0, 0, 0);
            s01 = __builtin_amdgcn_mfma_f32_16x16x32_bf16(th[0][kb], k1, s01, 0, 0, 0);
            s10 = __builtin_amdgcn_mfma_f32_16x16x32_bf16(th[1][kb], k0, s10, 0, 0, 0);
            s11 = __builtin_amdgcn_mfma_f32_16x16x32_bf16(th[1][kb], k1, s11, 0, 0, 0);
        }
        // ---- exp -> P relay (frag-major) + row-sum partials ----
        // value (q = qg*32+qs*16+quad*4+r, key = kh*32+nn*16+nidx) ->
        // frag f = (qg*2+qs)*2+kh, cell = (nn*2+pc_hi)*16 + quad*4+r, elem j=nidx&7
        #pragma unroll
        for (int r = 0; r < 4; r++) {
            float e = exp2f(s00[r] * SC); lrow[r] += e;
            Pbuf[b][(qg * 2 + 0) * 2 + kh][(0 * 2 + pc_hi) * 16 + quad * 4 + r][pj] = f2b(e);
        }
        #pragma unroll
        for (int r = 0; r < 4; r++) {
            float e = exp2f(s01[r] * SC); lrow[r] += e;
            Pbuf[b][(qg * 2 + 0) * 2 + kh][(1 * 2 + pc_hi) * 16 + quad * 4 + r][pj] = f2b(e);
        }
        #pragma unroll
        for (int r = 0; r < 4; r++) {
            float e = exp2f(s10[r] * SC); lrow[4 + r] += e;
            Pbuf[b][(qg * 2 + 1) * 2 + kh][(0 * 2 + pc_hi) * 16 + quad * 4 + r][pj] = f2b(e);
        }
        #pragma unroll
        for (int r = 0; r < 4; r++) {
            float e = exp2f(s11[r] * SC); lrow[4 + r] += e;
            Pbuf[b][(qg * 2 + 1) * 2 + kh][(1 * 2 + pc_hi) * 16 + quad * 4 + r][pj] = f2b(e);
        }
        // ---- stage K(t+1) into Kl[b^1] (regs prefetched last iter), prefetch K(t+2) ----
        if (t < 31) {
            #pragma unroll
            for (int rr = 0; rr < 4; rr++) *(short8*)(&Kl[b ^ 1][rr * 4096 + kfbase]) = kregs[rr];
            const int tn2 = (t + 2 < 32) ? t + 2 : 31;
            loadKregs(kregs, tn2);
        }
        __syncthreads();                                 // P(t) + Kl[t+1] ready
        // ---- PV: o[wave's 32 ch][128 q] += V * P ----
        #pragma unroll
        for (int qq = 0; qq < 8; qq++) {
            short8 pf0 = *(const short8*)(&Pbuf[b][qq * 2 + 0][lane][0]);
            short8 pf1 = *(const short8*)(&Pbuf[b][qq * 2 + 1][lane][0]);
            o[0][qq] = __builtin_amdgcn_mfma_f32_16x16x32_bf16(vregs[0], pf0, o[0][qq], 0, 0, 0);
            o[0][qq] = __builtin_amdgcn_mfma_f32_16x16x32_bf16(vregs[1], pf1, o[0][qq], 0, 0, 0);
            o[1][qq] = __builtin_amdgcn_mfma_f32_16x16x32_bf16(vregs[2], pf0, o[1][qq], 0, 0, 0);
            o[1][qq] = __builtin_amdgcn_mfma_f32_16x16x32_bf16(vregs[3], pf1, o[1][qq], 0, 0, 0);
        }
        loadVregs(vregs, (t + 1 < 32) ? t + 1 : 31);     // WAR-safe: PV consumed vregs
    }

    // ---- epilogue: partial l (reduce over key lanes, then over kh waves) ----
    #pragma unroll
    for (int i = 0; i < 8; i++) {
        float v = lrow[i];
        v += __shfl_xor(v, 1);
        v += __shfl_xor(v, 2);
        v += __shfl_xor(v, 4);
        v += __shfl_xor(v, 8);
        if (nidx == 0)
            Lbuf[kh][qg * 32 + (i >> 2) * 16 + quad * 4 + (i & 3)] = v;
    }
    __syncthreads();
    if (tid < 128)
        lw[(size_t)h * SEQ + seq0 + p0 + tid] = Lbuf[0][tid] + Lbuf[1][tid];
    // lane holds O[ch = w*32+mg*16+quad*4+r][q = qq*16+nidx]; store rows=q, cols=ch
    float* Op = Ow + ((size_t)h * SEQ + seq0 + p0) * CC;
    #pragma unroll
    for (int mg = 0; mg < 2; mg++)
        #pragma unroll
        for (int qq = 0; qq < 8; qq++)
            *(float4_t*)(Op + (size_t)(qq * 16 + nidx) * CC + w * 32 + mg * 16 + quad * 4) = o[mg][qq];
}

// ---- kernel 3b: combine key-halves: fT[q][ch] = (O0+O1)/(l0+l1) as bf16 ----
__global__ __launch_bounds__(256) void k_reduce(const float* __restrict__ Ow,
                                                const float* __restrict__ lw,
                                                unsigned short* __restrict__ fT) {
    const float4_t* O0 = (const float4_t*)Ow;
    const float4_t* O1 = (const float4_t*)(Ow + SEQ * CC);
    int i0 = blockIdx.x * 256 + threadIdx.x;             // grid 1024 x 4 iters
    #pragma unroll
    for (int j = 0; j < 4; j++) {
        int idx = j * 262144 + i0;                       // float4 index, SEQ*CC/4 total
        int row = idx >> 6;                              // 64 float4 per 256-ch row
        float li = 1.0f / (lw[row] + lw[SEQ + row]);
        float4_t a = O0[idx];
        float4_t b = O1[idx];
        short4_t pk;
        #pragma unroll
        for (int r = 0; r < 4; r++) pk[r] = (short)f2b((a[r] + b[r]) * li);
        *(short4_t*)(fT + (size_t)idx * 4) = pk;
    }
}

// ---- kernel 4: out[n][co][p] = x + b[co] + sum_k W[co][k]*fT[p][k] ----
__global__ __launch_bounds__(256) void k_final(const unsigned short* __restrict__ Wc,
                                               const float* __restrict__ bc,
                                               const unsigned short* __restrict__ fT,
                                               const float* __restrict__ x,
                                               float* __restrict__ out) {
    int w = threadIdx.x >> 6, lane = threadIdx.x & 63;
    int nidx = lane & 15, quad = lane >> 4;
    int n = blockIdx.z;
    int co0 = blockIdx.y * 64 + w * 16;
    int p0 = blockIdx.x * 64;
    float4_t acc[4];
    #pragma unroll
    for (int i = 0; i < 4; i++) acc[i] = (float4_t)(0.f);
    const unsigned short* arow = Wc + (size_t)(co0 + nidx) * CC + quad * 8;
    const unsigned short* brow = fT + ((size_t)n * HW + p0 + nidx) * CC + quad * 8;
    for (int ks = 0; ks < 8; ks++) {
        short8 a = *(const short8*)(arow + ks * 32);
        #pragma unroll
        for (int pb = 0; pb < 4; pb++) {
            short8 bb = *(const short8*)(brow + (size_t)pb * 16 * CC + ks * 32);
            acc[pb] = __builtin_amdgcn_mfma_f32_16x16x32_bf16(a, bb, acc[pb], 0, 0, 0);
        }
    }
    #pragma unroll
    for (int pb = 0; pb < 4; pb++) {
        #pragma unroll
        for (int r = 0; r < 4; r++) {
            int co = co0 + quad * 4 + r;
            size_t idx = ((size_t)n * CC + co) * HW + p0 + pb * 16 + nidx;
            out[idx] = x[idx] + bc[co] + acc[pb][r];
        }
    }
}

extern "C" void kernel_launch(void* const* d_in, const int* in_sizes, int n_in,
                              void* d_out, int out_size, void* d_ws, size_t ws_size,
                              hipStream_t stream) {
    const float* x       = (const float*)d_in[0];
    const float* theta_w = (const float*)d_in[1];
    const float* theta_b = (const float*)d_in[2];
    const float* phi_w   = (const float*)d_in[3];
    const float* phi_b   = (const float*)d_in[4];
    const float* conv1_w = (const float*)d_in[5];
    const float* conv1_b = (const float*)d_in[6];
    float* out = (float*)d_out;

    unsigned short* XT  = (unsigned short*)d_ws;  // [SEQ][256] bf16
    unsigned short* gb  = XT  + SEQ * CC;         // [N][256][4096]
    unsigned short* thT = gb  + SEQ * CC;         // [SEQ][256]
    unsigned short* phT = thT + SEQ * CC;         // [SEQ][256]
    unsigned short* fT  = phT + SEQ * CC;         // [SEQ][256]
    unsigned short* Wbt = fT  + SEQ * CC;
    unsigned short* Wbp = Wbt + 65536;
    unsigned short* Wbc = Wbp + 65536;
    float* Ow = (float*)(Wbc + 65536);            // [2][SEQ][256] fp32 partial O
    float* lw = Ow + 2 * SEQ * CC;                // [2][SEQ] fp32 partial l

    k_prep<<<dim3(64, 4, 4), 256, 0, stream>>>(x, theta_w, phi_w, conv1_w, XT, gb, Wbt, Wbp, Wbc);
    k_proj<<<dim3(256, 2), 256, 0, stream>>>(XT, Wbt, Wbp, theta_b, phi_b, thT, phT);
    k_attn<<<dim3(256), 512, 0, stream>>>(thT, phT, gb, Ow, lw);
    k_reduce<<<dim3(1024), 256, 0, stream>>>(Ow, lw, fT);
    k_final<<<dim3(64, 4, 4), 256, 0, stream>>>(Wbc, conv1_b, fT, x, out);
}